// Round 6
// baseline (138.297 us; speedup 1.0000x reference)
//
#include <hip/hip_runtime.h>
#include <hip/hip_fp16.h>
#include <math.h>

#define NN 20000
#define EE 320000
#define CIN 16
#define COUT 16
#define R2C 0.25f
#define P_OFF 81920 // cnt occupies [0, NN*4) = 80000 B; P starts after, 16B-aligned
// P layout (fp16): P[cell][node][out] -> P[((size_t)cell*NN + n)*16 + o], 64 cells -> 41 MB

// ---------------- zero out + counts ----------------
__global__ __launch_bounds__(256) void k_zero(float* __restrict__ out, int* __restrict__ cnt) {
    int i = blockIdx.x * 256 + threadIdx.x;
    if (i < NN * COUT) out[i] = 0.0f;
    if (i < NN) cnt[i] = 0;
}

// ---------------- P GEMM: P[cell][n][o] = sum_ci feat[n][ci] * filters[cell][ci][o] ----------------
// Grid (ceil(NN/64), 4): blockIdx.y picks 16 cells -> 16 KB LDS stage.
// Block 256 = 4 waves; wave w owns cells [w*4, w*4+4). Lane = (ns, q); each lane
// processes 4 nodes {base+ns+16r} -> 16 FLOP per LDS b128 load.
// fp32 accumulate, fp16 store: lane (ns,q) writes 8 B contiguous -> 512 B/wave-store.
__global__ __launch_bounds__(256) void k_pgemm(const float* __restrict__ feat,
                                               const float* __restrict__ filt,
                                               __half* __restrict__ P) {
    __shared__ float fl[16 * 256]; // 16 cells * 16ci * 16co

    {
        const float4* src = (const float4*)(filt + (size_t)blockIdx.y * 16 * 256);
        float4* dst = (float4*)fl;
        #pragma unroll
        for (int r = 0; r < 4; ++r)
            dst[r * 256 + threadIdx.x] = src[r * 256 + threadIdx.x];
    }
    __syncthreads();

    int lane  = threadIdx.x & 63;
    int w     = threadIdx.x >> 6;   // wave -> cell sub-group
    int q     = lane & 3;           // output quad
    int ns    = lane >> 2;          // node sub 0..15
    int nbase = blockIdx.x * 64;

    float f[4][16];
    #pragma unroll
    for (int r = 0; r < 4; ++r) {
        int n = nbase + ns + 16 * r;
        if (n < NN) {
            const float4* fp = (const float4*)(feat + (size_t)n * 16);
            float4 f0 = fp[0], f1 = fp[1], f2 = fp[2], f3 = fp[3];
            f[r][0]=f0.x; f[r][1]=f0.y; f[r][2]=f0.z; f[r][3]=f0.w;
            f[r][4]=f1.x; f[r][5]=f1.y; f[r][6]=f1.z; f[r][7]=f1.w;
            f[r][8]=f2.x; f[r][9]=f2.y; f[r][10]=f2.z; f[r][11]=f2.w;
            f[r][12]=f3.x; f[r][13]=f3.y; f[r][14]=f3.z; f[r][15]=f3.w;
        } else {
            #pragma unroll
            for (int ci = 0; ci < 16; ++ci) f[r][ci] = 0.0f;
        }
    }

    #pragma unroll
    for (int c = 0; c < 4; ++c) {
        int cell = w * 4 + c;
        float4 acc0 = make_float4(0.f,0.f,0.f,0.f);
        float4 acc1 = acc0, acc2 = acc0, acc3 = acc0;
        const float4* row = (const float4*)(fl + cell * 256) + q;
        #pragma unroll
        for (int ci = 0; ci < 16; ++ci) {
            float4 wv = row[ci * 4];
            float v0 = f[0][ci], v1 = f[1][ci], v2 = f[2][ci], v3 = f[3][ci];
            acc0.x = fmaf(v0, wv.x, acc0.x); acc0.y = fmaf(v0, wv.y, acc0.y);
            acc0.z = fmaf(v0, wv.z, acc0.z); acc0.w = fmaf(v0, wv.w, acc0.w);
            acc1.x = fmaf(v1, wv.x, acc1.x); acc1.y = fmaf(v1, wv.y, acc1.y);
            acc1.z = fmaf(v1, wv.z, acc1.z); acc1.w = fmaf(v1, wv.w, acc1.w);
            acc2.x = fmaf(v2, wv.x, acc2.x); acc2.y = fmaf(v2, wv.y, acc2.y);
            acc2.z = fmaf(v2, wv.z, acc2.z); acc2.w = fmaf(v2, wv.w, acc2.w);
            acc3.x = fmaf(v3, wv.x, acc3.x); acc3.y = fmaf(v3, wv.y, acc3.y);
            acc3.z = fmaf(v3, wv.z, acc3.z); acc3.w = fmaf(v3, wv.w, acc3.w);
        }
        size_t cell_g = (size_t)(blockIdx.y * 16 + cell);
        float4 accs[4] = {acc0, acc1, acc2, acc3};
        #pragma unroll
        for (int r = 0; r < 4; ++r) {
            int n = nbase + ns + 16 * r;
            if (n < NN) {
                __half2 lo = __float22half2_rn(make_float2(accs[r].x, accs[r].y));
                __half2 hi = __float22half2_rn(make_float2(accs[r].z, accs[r].w));
                uint2 u;
                u.x = *(unsigned int*)&lo;
                u.y = *(unsigned int*)&hi;
                *(uint2*)(P + (cell_g * NN + n) * 16 + q * 4) = u;
            }
        }
    }
}

// ---------------- geometry helper (device inline) ----------------
__device__ __forceinline__ bool edge_geom(const float* __restrict__ pos, int row, int col,
                                          float& win,
                                          int ia[2], int jb[2], int kc[2],
                                          float wa[2], float wb[2], float wc[2]) {
    float rx = pos[col*3+0] - pos[row*3+0];
    float ry = pos[col*3+1] - pos[row*3+1];
    float rz = pos[col*3+2] - pos[row*3+2];
    float d2 = rx*rx + ry*ry + rz*rz;
    if (!(d2 < R2C)) return false;           // window == 0 -> contributes nothing
    float u = 1.0f - d2 / R2C;
    win = u * u * u;
    float nr = sqrtf(d2);
    float s  = tanhf(nr) / (nr + 1e-8f);
    float gx = (rx * s + 1.0f) * 1.5f;       // c-axis (k index)
    float gy = (ry * s + 1.0f) * 1.5f;       // b-axis (j index)
    float gz = (rz * s + 1.0f) * 1.5f;       // a-axis (i index)
    float af = floorf(gz), bf = floorf(gy), cf = floorf(gx);
    int ia0 = min(max((int)af, 0), 3);
    int ib0 = min(max((int)bf, 0), 3);
    int ic0 = min(max((int)cf, 0), 3);
    ia[0] = ia0; ia[1] = min(ia0 + 1, 3);
    jb[0] = ib0; jb[1] = min(ib0 + 1, 3);
    kc[0] = ic0; kc[1] = min(ic0 + 1, 3);
    float ad = gz - af, bd = gy - bf, cd = gx - cf;
    wa[0] = 1.0f - ad; wa[1] = ad;
    wb[0] = 1.0f - bd; wb[1] = bd;
    wc[0] = 1.0f - cd; wc[1] = cd;
    return true;
}

// ---------------- edge pass: 2 threads per edge, each owns 8 channels ----------------
// lanes 2k,2k+1 share edge e; per corner each lane loads one 16B half8 -> 32B/corner/edge.
__global__ __launch_bounds__(256) void k_edge(const float* __restrict__ pos,
                                              const int* __restrict__ ei,
                                              const __half* __restrict__ P,
                                              float* __restrict__ out,
                                              int* __restrict__ cnt) {
    int t = blockIdx.x * 256 + threadIdx.x;
    int e = t >> 1;
    int h = t & 1;                   // channel half: outputs [h*8, h*8+8)
    if (e >= EE) return;
    int row = ei[e];
    int col = ei[EE + e];
    if (h == 0) atomicAdd(&cnt[row], 1);

    float win;
    int ia[2], jb[2], kc[2];
    float wa[2], wb[2], wc[2];
    if (!edge_geom(pos, row, col, win, ia, jb, kc, wa, wb, wc)) return;

    float4 acc0 = make_float4(0.f,0.f,0.f,0.f);
    float4 acc1 = acc0;
    const __half* Pq = P + (size_t)col * 16 + h * 8;
    #pragma unroll
    for (int da = 0; da < 2; ++da)
    #pragma unroll
    for (int db = 0; db < 2; ++db)
    #pragma unroll
    for (int dc = 0; dc < 2; ++dc) {
        float w = wa[da] * wb[db] * wc[dc] * win;
        int cell = ia[da]*16 + jb[db]*4 + kc[dc];
        uint4 raw = *(const uint4*)(Pq + (size_t)cell * NN * 16);
        __half2* hp = (__half2*)&raw;
        float2 p0 = __half22float2(hp[0]);
        float2 p1 = __half22float2(hp[1]);
        float2 p2 = __half22float2(hp[2]);
        float2 p3 = __half22float2(hp[3]);
        acc0.x = fmaf(w, p0.x, acc0.x); acc0.y = fmaf(w, p0.y, acc0.y);
        acc0.z = fmaf(w, p1.x, acc0.z); acc0.w = fmaf(w, p1.y, acc0.w);
        acc1.x = fmaf(w, p2.x, acc1.x); acc1.y = fmaf(w, p2.y, acc1.y);
        acc1.z = fmaf(w, p3.x, acc1.z); acc1.w = fmaf(w, p3.y, acc1.w);
    }
    float* op = out + (size_t)row * 16 + h * 8;
    atomicAdd(op+0, acc0.x);
    atomicAdd(op+1, acc0.y);
    atomicAdd(op+2, acc0.z);
    atomicAdd(op+3, acc0.w);
    atomicAdd(op+4, acc1.x);
    atomicAdd(op+5, acc1.y);
    atomicAdd(op+6, acc1.z);
    atomicAdd(op+7, acc1.w);
}

// ---------------- fallback: direct edge kernel, filters from global (slow but correct) ----------------
__global__ __launch_bounds__(256) void k_edge_direct(const float* __restrict__ pos,
                                                     const float* __restrict__ feat,
                                                     const float* __restrict__ filt,
                                                     const int* __restrict__ ei,
                                                     float* __restrict__ out,
                                                     int* __restrict__ cnt) {
    int e = blockIdx.x * 256 + threadIdx.x;
    if (e >= EE) return;
    int row = ei[e];
    int col = ei[EE + e];
    atomicAdd(&cnt[row], 1);

    float win;
    int ia[2], jb[2], kc[2];
    float wa[2], wb[2], wc[2];
    if (!edge_geom(pos, row, col, win, ia, jb, kc, wa, wb, wc)) return;

    float fv[16];
    const float4* fp = (const float4*)(feat + (size_t)col * 16);
    float4 f0 = fp[0], f1 = fp[1], f2 = fp[2], f3 = fp[3];
    fv[0]=f0.x; fv[1]=f0.y; fv[2]=f0.z; fv[3]=f0.w;
    fv[4]=f1.x; fv[5]=f1.y; fv[6]=f1.z; fv[7]=f1.w;
    fv[8]=f2.x; fv[9]=f2.y; fv[10]=f2.z; fv[11]=f2.w;
    fv[12]=f3.x; fv[13]=f3.y; fv[14]=f3.z; fv[15]=f3.w;

    float4 a0 = make_float4(0.f,0.f,0.f,0.f);
    float4 a1 = a0, a2 = a0, a3 = a0;
    for (int da = 0; da < 2; ++da)
    for (int db = 0; db < 2; ++db)
    for (int dc = 0; dc < 2; ++dc) {
        float w = wa[da] * wb[db] * wc[dc] * win;
        const float* fb = filt + (size_t)(ia[da]*16 + jb[db]*4 + kc[dc]) * 256;
        #pragma unroll
        for (int ci = 0; ci < 16; ++ci) {
            float c = w * fv[ci];
            const float4* r4 = (const float4*)(fb + ci * 16);
            float4 w0 = r4[0], w1 = r4[1], w2 = r4[2], w3 = r4[3];
            a0.x = fmaf(c, w0.x, a0.x); a0.y = fmaf(c, w0.y, a0.y);
            a0.z = fmaf(c, w0.z, a0.z); a0.w = fmaf(c, w0.w, a0.w);
            a1.x = fmaf(c, w1.x, a1.x); a1.y = fmaf(c, w1.y, a1.y);
            a1.z = fmaf(c, w1.z, a1.z); a1.w = fmaf(c, w1.w, a1.w);
            a2.x = fmaf(c, w2.x, a2.x); a2.y = fmaf(c, w2.y, a2.y);
            a2.z = fmaf(c, w2.z, a2.z); a2.w = fmaf(c, w2.w, a2.w);
            a3.x = fmaf(c, w3.x, a3.x); a3.y = fmaf(c, w3.y, a3.y);
            a3.z = fmaf(c, w3.z, a3.z); a3.w = fmaf(c, w3.w, a3.w);
        }
    }
    float* op = out + (size_t)row * 16;
    atomicAdd(op+0,  a0.x); atomicAdd(op+1,  a0.y); atomicAdd(op+2,  a0.z); atomicAdd(op+3,  a0.w);
    atomicAdd(op+4,  a1.x); atomicAdd(op+5,  a1.y); atomicAdd(op+6,  a1.z); atomicAdd(op+7,  a1.w);
    atomicAdd(op+8,  a2.x); atomicAdd(op+9,  a2.y); atomicAdd(op+10, a2.z); atomicAdd(op+11, a2.w);
    atomicAdd(op+12, a3.x); atomicAdd(op+13, a3.y); atomicAdd(op+14, a3.z); atomicAdd(op+15, a3.w);
}

// ---------------- divide by max(cnt,1) ----------------
__global__ __launch_bounds__(256) void k_div(float* __restrict__ out, const int* __restrict__ cnt) {
    int i = blockIdx.x * 256 + threadIdx.x;
    if (i >= NN * COUT) return;
    int c = cnt[i >> 4];
    float denom = (c > 1) ? (float)c : 1.0f;
    out[i] = out[i] / denom;
}

extern "C" void kernel_launch(void* const* d_in, const int* in_sizes, int n_in,
                              void* d_out, int out_size, void* d_ws, size_t ws_size,
                              hipStream_t stream) {
    const float* pos  = (const float*)d_in[0];
    const float* feat = (const float*)d_in[1];
    const float* filt = (const float*)d_in[2];
    const int*   ei   = (const int*)d_in[3];
    float* out = (float*)d_out;

    int* cnt = (int*)d_ws;
    size_t need = (size_t)P_OFF + (size_t)64 * NN * 16 * sizeof(__half);

    k_zero<<<(NN * COUT + 255) / 256, 256, 0, stream>>>(out, cnt);

    if (ws_size >= need) {
        __half* P = (__half*)((char*)d_ws + P_OFF);
        dim3 pg((NN + 63) / 64, 4);
        k_pgemm<<<pg, 256, 0, stream>>>(feat, filt, P);
        k_edge<<<(EE * 2 + 255) / 256, 256, 0, stream>>>(pos, ei, P, out, cnt);
    } else {
        k_edge_direct<<<(EE + 255) / 256, 256, 0, stream>>>(pos, feat, filt, ei, out, cnt);
    }

    k_div<<<(NN * COUT + 255) / 256, 256, 0, stream>>>(out, cnt);
}

// Round 7
// 119.357 us; speedup vs baseline: 1.1587x; 1.1587x over previous
//
#include <hip/hip_runtime.h>
#include <hip/hip_fp16.h>
#include <math.h>

#define NN 20000
#define EE 320000
#define CIN 16
#define COUT 16
#define R2C 0.25f
#define P_OFF 81920 // cnt occupies [0, NN*4) = 80000 B; P starts after, 16B-aligned
// P layout (fp16): P[cell][node][out] -> P[((size_t)cell*NN + n)*16 + o], 64 cells -> 41 MB

// ---------------- zero out + counts ----------------
__global__ __launch_bounds__(256) void k_zero(float* __restrict__ out, int* __restrict__ cnt) {
    int i = blockIdx.x * 256 + threadIdx.x;
    if (i < NN * COUT) out[i] = 0.0f;
    if (i < NN) cnt[i] = 0;
}

// ---------------- P GEMM: P[cell][n][o] = sum_ci feat[n][ci] * filters[cell][ci][o] ----------------
// Grid (ceil(NN/64), 4): blockIdx.y picks 16 cells -> 16 KB LDS stage.
// Block 256 = 4 waves; wave w owns cells [w*4, w*4+4). Lane = (ns, q); each lane
// processes 4 nodes {base+ns+16r} -> 16 FLOP per LDS b128 load.
// fp32 accumulate, fp16 store: lane (ns,q) writes 8 B contiguous -> 512 B/wave-store.
__global__ __launch_bounds__(256) void k_pgemm(const float* __restrict__ feat,
                                               const float* __restrict__ filt,
                                               __half* __restrict__ P) {
    __shared__ float fl[16 * 256]; // 16 cells * 16ci * 16co

    {
        const float4* src = (const float4*)(filt + (size_t)blockIdx.y * 16 * 256);
        float4* dst = (float4*)fl;
        #pragma unroll
        for (int r = 0; r < 4; ++r)
            dst[r * 256 + threadIdx.x] = src[r * 256 + threadIdx.x];
    }
    __syncthreads();

    int lane  = threadIdx.x & 63;
    int w     = threadIdx.x >> 6;   // wave -> cell sub-group
    int q     = lane & 3;           // output quad
    int ns    = lane >> 2;          // node sub 0..15
    int nbase = blockIdx.x * 64;

    float f[4][16];
    #pragma unroll
    for (int r = 0; r < 4; ++r) {
        int n = nbase + ns + 16 * r;
        if (n < NN) {
            const float4* fp = (const float4*)(feat + (size_t)n * 16);
            float4 f0 = fp[0], f1 = fp[1], f2 = fp[2], f3 = fp[3];
            f[r][0]=f0.x; f[r][1]=f0.y; f[r][2]=f0.z; f[r][3]=f0.w;
            f[r][4]=f1.x; f[r][5]=f1.y; f[r][6]=f1.z; f[r][7]=f1.w;
            f[r][8]=f2.x; f[r][9]=f2.y; f[r][10]=f2.z; f[r][11]=f2.w;
            f[r][12]=f3.x; f[r][13]=f3.y; f[r][14]=f3.z; f[r][15]=f3.w;
        } else {
            #pragma unroll
            for (int ci = 0; ci < 16; ++ci) f[r][ci] = 0.0f;
        }
    }

    #pragma unroll
    for (int c = 0; c < 4; ++c) {
        int cell = w * 4 + c;
        float4 acc0 = make_float4(0.f,0.f,0.f,0.f);
        float4 acc1 = acc0, acc2 = acc0, acc3 = acc0;
        const float4* row = (const float4*)(fl + cell * 256) + q;
        #pragma unroll
        for (int ci = 0; ci < 16; ++ci) {
            float4 wv = row[ci * 4];
            float v0 = f[0][ci], v1 = f[1][ci], v2 = f[2][ci], v3 = f[3][ci];
            acc0.x = fmaf(v0, wv.x, acc0.x); acc0.y = fmaf(v0, wv.y, acc0.y);
            acc0.z = fmaf(v0, wv.z, acc0.z); acc0.w = fmaf(v0, wv.w, acc0.w);
            acc1.x = fmaf(v1, wv.x, acc1.x); acc1.y = fmaf(v1, wv.y, acc1.y);
            acc1.z = fmaf(v1, wv.z, acc1.z); acc1.w = fmaf(v1, wv.w, acc1.w);
            acc2.x = fmaf(v2, wv.x, acc2.x); acc2.y = fmaf(v2, wv.y, acc2.y);
            acc2.z = fmaf(v2, wv.z, acc2.z); acc2.w = fmaf(v2, wv.w, acc2.w);
            acc3.x = fmaf(v3, wv.x, acc3.x); acc3.y = fmaf(v3, wv.y, acc3.y);
            acc3.z = fmaf(v3, wv.z, acc3.z); acc3.w = fmaf(v3, wv.w, acc3.w);
        }
        size_t cell_g = (size_t)(blockIdx.y * 16 + cell);
        float4 accs[4] = {acc0, acc1, acc2, acc3};
        #pragma unroll
        for (int r = 0; r < 4; ++r) {
            int n = nbase + ns + 16 * r;
            if (n < NN) {
                __half2 lo = __float22half2_rn(make_float2(accs[r].x, accs[r].y));
                __half2 hi = __float22half2_rn(make_float2(accs[r].z, accs[r].w));
                uint2 u;
                u.x = *(unsigned int*)&lo;
                u.y = *(unsigned int*)&hi;
                *(uint2*)(P + (cell_g * NN + n) * 16 + q * 4) = u;
            }
        }
    }
}

// ---------------- geometry helper (device inline) ----------------
__device__ __forceinline__ bool edge_geom(const float* __restrict__ pos, int row, int col,
                                          float& win,
                                          int ia[2], int jb[2], int kc[2],
                                          float wa[2], float wb[2], float wc[2]) {
    float rx = pos[col*3+0] - pos[row*3+0];
    float ry = pos[col*3+1] - pos[row*3+1];
    float rz = pos[col*3+2] - pos[row*3+2];
    float d2 = rx*rx + ry*ry + rz*rz;
    if (!(d2 < R2C)) return false;           // window == 0 -> contributes nothing
    float u = 1.0f - d2 / R2C;
    win = u * u * u;
    float nr = sqrtf(d2);
    float s  = tanhf(nr) / (nr + 1e-8f);
    float gx = (rx * s + 1.0f) * 1.5f;       // c-axis (k index)
    float gy = (ry * s + 1.0f) * 1.5f;       // b-axis (j index)
    float gz = (rz * s + 1.0f) * 1.5f;       // a-axis (i index)
    float af = floorf(gz), bf = floorf(gy), cf = floorf(gx);
    int ia0 = min(max((int)af, 0), 3);
    int ib0 = min(max((int)bf, 0), 3);
    int ic0 = min(max((int)cf, 0), 3);
    ia[0] = ia0; ia[1] = min(ia0 + 1, 3);
    jb[0] = ib0; jb[1] = min(ib0 + 1, 3);
    kc[0] = ic0; kc[1] = min(ic0 + 1, 3);
    float ad = gz - af, bd = gy - bf, cd = gx - cf;
    wa[0] = 1.0f - ad; wa[1] = ad;
    wb[0] = 1.0f - bd; wb[1] = bd;
    wc[0] = 1.0f - cd; wc[1] = cd;
    return true;
}

// ---------------- edge pass: 4 threads per edge, each owns a channel quad ----------------
// lanes 4k..4k+3 share edge e; per corner each lane loads one 8B half4 -> 32B/corner/edge.
__global__ __launch_bounds__(256) void k_edge(const float* __restrict__ pos,
                                              const int* __restrict__ ei,
                                              const __half* __restrict__ P,
                                              float* __restrict__ out,
                                              int* __restrict__ cnt) {
    int t = blockIdx.x * 256 + threadIdx.x;
    int e = t >> 2;
    int q = t & 3;                   // channel quad: outputs [q*4, q*4+4)
    if (e >= EE) return;
    int row = ei[e];
    int col = ei[EE + e];
    if (q == 0) atomicAdd(&cnt[row], 1);

    float win;
    int ia[2], jb[2], kc[2];
    float wa[2], wb[2], wc[2];
    if (!edge_geom(pos, row, col, win, ia, jb, kc, wa, wb, wc)) return;

    float4 acc = make_float4(0.f,0.f,0.f,0.f);
    const __half* Pq = P + (size_t)col * 16 + q * 4;
    #pragma unroll
    for (int da = 0; da < 2; ++da)
    #pragma unroll
    for (int db = 0; db < 2; ++db)
    #pragma unroll
    for (int dc = 0; dc < 2; ++dc) {
        float w = wa[da] * wb[db] * wc[dc] * win;
        int cell = ia[da]*16 + jb[db]*4 + kc[dc];
        uint2 raw = *(const uint2*)(Pq + (size_t)cell * NN * 16);
        __half2* hp = (__half2*)&raw;
        float2 p0 = __half22float2(hp[0]);
        float2 p1 = __half22float2(hp[1]);
        acc.x = fmaf(w, p0.x, acc.x);
        acc.y = fmaf(w, p0.y, acc.y);
        acc.z = fmaf(w, p1.x, acc.z);
        acc.w = fmaf(w, p1.y, acc.w);
    }
    float* op = out + (size_t)row * 16 + q * 4;
    atomicAdd(op+0, acc.x);
    atomicAdd(op+1, acc.y);
    atomicAdd(op+2, acc.z);
    atomicAdd(op+3, acc.w);
}

// ---------------- fallback: direct edge kernel, filters from global (slow but correct) ----------------
__global__ __launch_bounds__(256) void k_edge_direct(const float* __restrict__ pos,
                                                     const float* __restrict__ feat,
                                                     const float* __restrict__ filt,
                                                     const int* __restrict__ ei,
                                                     float* __restrict__ out,
                                                     int* __restrict__ cnt) {
    int e = blockIdx.x * 256 + threadIdx.x;
    if (e >= EE) return;
    int row = ei[e];
    int col = ei[EE + e];
    atomicAdd(&cnt[row], 1);

    float win;
    int ia[2], jb[2], kc[2];
    float wa[2], wb[2], wc[2];
    if (!edge_geom(pos, row, col, win, ia, jb, kc, wa, wb, wc)) return;

    float fv[16];
    const float4* fp = (const float4*)(feat + (size_t)col * 16);
    float4 f0 = fp[0], f1 = fp[1], f2 = fp[2], f3 = fp[3];
    fv[0]=f0.x; fv[1]=f0.y; fv[2]=f0.z; fv[3]=f0.w;
    fv[4]=f1.x; fv[5]=f1.y; fv[6]=f1.z; fv[7]=f1.w;
    fv[8]=f2.x; fv[9]=f2.y; fv[10]=f2.z; fv[11]=f2.w;
    fv[12]=f3.x; fv[13]=f3.y; fv[14]=f3.z; fv[15]=f3.w;

    float4 a0 = make_float4(0.f,0.f,0.f,0.f);
    float4 a1 = a0, a2 = a0, a3 = a0;
    for (int da = 0; da < 2; ++da)
    for (int db = 0; db < 2; ++db)
    for (int dc = 0; dc < 2; ++dc) {
        float w = wa[da] * wb[db] * wc[dc] * win;
        const float* fb = filt + (size_t)(ia[da]*16 + jb[db]*4 + kc[dc]) * 256;
        #pragma unroll
        for (int ci = 0; ci < 16; ++ci) {
            float c = w * fv[ci];
            const float4* r4 = (const float4*)(fb + ci * 16);
            float4 w0 = r4[0], w1 = r4[1], w2 = r4[2], w3 = r4[3];
            a0.x = fmaf(c, w0.x, a0.x); a0.y = fmaf(c, w0.y, a0.y);
            a0.z = fmaf(c, w0.z, a0.z); a0.w = fmaf(c, w0.w, a0.w);
            a1.x = fmaf(c, w1.x, a1.x); a1.y = fmaf(c, w1.y, a1.y);
            a1.z = fmaf(c, w1.z, a1.z); a1.w = fmaf(c, w1.w, a1.w);
            a2.x = fmaf(c, w2.x, a2.x); a2.y = fmaf(c, w2.y, a2.y);
            a2.z = fmaf(c, w2.z, a2.z); a2.w = fmaf(c, w2.w, a2.w);
            a3.x = fmaf(c, w3.x, a3.x); a3.y = fmaf(c, w3.y, a3.y);
            a3.z = fmaf(c, w3.z, a3.z); a3.w = fmaf(c, w3.w, a3.w);
        }
    }
    float* op = out + (size_t)row * 16;
    atomicAdd(op+0,  a0.x); atomicAdd(op+1,  a0.y); atomicAdd(op+2,  a0.z); atomicAdd(op+3,  a0.w);
    atomicAdd(op+4,  a1.x); atomicAdd(op+5,  a1.y); atomicAdd(op+6,  a1.z); atomicAdd(op+7,  a1.w);
    atomicAdd(op+8,  a2.x); atomicAdd(op+9,  a2.y); atomicAdd(op+10, a2.z); atomicAdd(op+11, a2.w);
    atomicAdd(op+12, a3.x); atomicAdd(op+13, a3.y); atomicAdd(op+14, a3.z); atomicAdd(op+15, a3.w);
}

// ---------------- divide by max(cnt,1) ----------------
__global__ __launch_bounds__(256) void k_div(float* __restrict__ out, const int* __restrict__ cnt) {
    int i = blockIdx.x * 256 + threadIdx.x;
    if (i >= NN * COUT) return;
    int c = cnt[i >> 4];
    float denom = (c > 1) ? (float)c : 1.0f;
    out[i] = out[i] / denom;
}

extern "C" void kernel_launch(void* const* d_in, const int* in_sizes, int n_in,
                              void* d_out, int out_size, void* d_ws, size_t ws_size,
                              hipStream_t stream) {
    const float* pos  = (const float*)d_in[0];
    const float* feat = (const float*)d_in[1];
    const float* filt = (const float*)d_in[2];
    const int*   ei   = (const int*)d_in[3];
    float* out = (float*)d_out;

    int* cnt = (int*)d_ws;
    size_t need = (size_t)P_OFF + (size_t)64 * NN * 16 * sizeof(__half);

    k_zero<<<(NN * COUT + 255) / 256, 256, 0, stream>>>(out, cnt);

    if (ws_size >= need) {
        __half* P = (__half*)((char*)d_ws + P_OFF);
        dim3 pg((NN + 63) / 64, 4);
        k_pgemm<<<pg, 256, 0, stream>>>(feat, filt, P);
        k_edge<<<(EE * 4 + 255) / 256, 256, 0, stream>>>(pos, ei, P, out, cnt);
    } else {
        k_edge_direct<<<(EE + 255) / 256, 256, 0, stream>>>(pos, feat, filt, ei, out, cnt);
    }

    k_div<<<(NN * COUT + 255) / 256, 256, 0, stream>>>(out, cnt);
}

// Round 8
// 108.692 us; speedup vs baseline: 1.2724x; 1.0981x over previous
//
#include <hip/hip_runtime.h>
#include <hip/hip_fp16.h>
#include <math.h>

#define NN 20000
#define EE 320000
#define CIN 16
#define COUT 16
#define R2C 0.25f
#define P_OFF 81920 // cnt occupies [0, NN*4) = 80000 B; P starts after, 16B-aligned
// P layout (fp16): P[cell][node][out] -> P[((size_t)cell*NN + n)*16 + o], 64 cells -> 41 MB

// ---------------- zero out + counts ----------------
__global__ __launch_bounds__(256) void k_zero(float* __restrict__ out, int* __restrict__ cnt) {
    int i = blockIdx.x * 256 + threadIdx.x;
    if (i < NN * COUT) out[i] = 0.0f;
    if (i < NN) cnt[i] = 0;
}

// ---------------- P GEMM: P[cell][n][o] = sum_ci feat[n][ci] * filters[cell][ci][o] ----------------
// Grid (ceil(NN/64), 4): blockIdx.y picks 16 cells -> 16 KB LDS stage.
// Block 256 = 4 waves; wave w owns cells [w*4, w*4+4). Lane = (ns, q); each lane
// processes 4 nodes {base+ns+16r} -> 16 FLOP per LDS b128 load.
// fp32 accumulate, fp16 store: lane (ns,q) writes 8 B contiguous -> 512 B/wave-store.
__global__ __launch_bounds__(256) void k_pgemm(const float* __restrict__ feat,
                                               const float* __restrict__ filt,
                                               __half* __restrict__ P) {
    __shared__ float fl[16 * 256]; // 16 cells * 16ci * 16co

    {
        const float4* src = (const float4*)(filt + (size_t)blockIdx.y * 16 * 256);
        float4* dst = (float4*)fl;
        #pragma unroll
        for (int r = 0; r < 4; ++r)
            dst[r * 256 + threadIdx.x] = src[r * 256 + threadIdx.x];
    }
    __syncthreads();

    int lane  = threadIdx.x & 63;
    int w     = threadIdx.x >> 6;   // wave -> cell sub-group
    int q     = lane & 3;           // output quad
    int ns    = lane >> 2;          // node sub 0..15
    int nbase = blockIdx.x * 64;

    float f[4][16];
    #pragma unroll
    for (int r = 0; r < 4; ++r) {
        int n = nbase + ns + 16 * r;
        if (n < NN) {
            const float4* fp = (const float4*)(feat + (size_t)n * 16);
            float4 f0 = fp[0], f1 = fp[1], f2 = fp[2], f3 = fp[3];
            f[r][0]=f0.x; f[r][1]=f0.y; f[r][2]=f0.z; f[r][3]=f0.w;
            f[r][4]=f1.x; f[r][5]=f1.y; f[r][6]=f1.z; f[r][7]=f1.w;
            f[r][8]=f2.x; f[r][9]=f2.y; f[r][10]=f2.z; f[r][11]=f2.w;
            f[r][12]=f3.x; f[r][13]=f3.y; f[r][14]=f3.z; f[r][15]=f3.w;
        } else {
            #pragma unroll
            for (int ci = 0; ci < 16; ++ci) f[r][ci] = 0.0f;
        }
    }

    #pragma unroll
    for (int c = 0; c < 4; ++c) {
        int cell = w * 4 + c;
        float4 acc0 = make_float4(0.f,0.f,0.f,0.f);
        float4 acc1 = acc0, acc2 = acc0, acc3 = acc0;
        const float4* row = (const float4*)(fl + cell * 256) + q;
        #pragma unroll
        for (int ci = 0; ci < 16; ++ci) {
            float4 wv = row[ci * 4];
            float v0 = f[0][ci], v1 = f[1][ci], v2 = f[2][ci], v3 = f[3][ci];
            acc0.x = fmaf(v0, wv.x, acc0.x); acc0.y = fmaf(v0, wv.y, acc0.y);
            acc0.z = fmaf(v0, wv.z, acc0.z); acc0.w = fmaf(v0, wv.w, acc0.w);
            acc1.x = fmaf(v1, wv.x, acc1.x); acc1.y = fmaf(v1, wv.y, acc1.y);
            acc1.z = fmaf(v1, wv.z, acc1.z); acc1.w = fmaf(v1, wv.w, acc1.w);
            acc2.x = fmaf(v2, wv.x, acc2.x); acc2.y = fmaf(v2, wv.y, acc2.y);
            acc2.z = fmaf(v2, wv.z, acc2.z); acc2.w = fmaf(v2, wv.w, acc2.w);
            acc3.x = fmaf(v3, wv.x, acc3.x); acc3.y = fmaf(v3, wv.y, acc3.y);
            acc3.z = fmaf(v3, wv.z, acc3.z); acc3.w = fmaf(v3, wv.w, acc3.w);
        }
        size_t cell_g = (size_t)(blockIdx.y * 16 + cell);
        float4 accs[4] = {acc0, acc1, acc2, acc3};
        #pragma unroll
        for (int r = 0; r < 4; ++r) {
            int n = nbase + ns + 16 * r;
            if (n < NN) {
                __half2 lo = __float22half2_rn(make_float2(accs[r].x, accs[r].y));
                __half2 hi = __float22half2_rn(make_float2(accs[r].z, accs[r].w));
                uint2 u;
                u.x = *(unsigned int*)&lo;
                u.y = *(unsigned int*)&hi;
                *(uint2*)(P + (cell_g * NN + n) * 16 + q * 4) = u;
            }
        }
    }
}

// ---------------- geometry helper (device inline) ----------------
__device__ __forceinline__ bool edge_geom(const float* __restrict__ pos, int row, int col,
                                          float& win,
                                          int ia[2], int jb[2], int kc[2],
                                          float wa[2], float wb[2], float wc[2]) {
    float rx = pos[col*3+0] - pos[row*3+0];
    float ry = pos[col*3+1] - pos[row*3+1];
    float rz = pos[col*3+2] - pos[row*3+2];
    float d2 = rx*rx + ry*ry + rz*rz;
    if (!(d2 < R2C)) return false;           // window == 0 -> contributes nothing
    float u = 1.0f - d2 / R2C;
    win = u * u * u;
    float nr = sqrtf(d2);
    float s  = tanhf(nr) / (nr + 1e-8f);
    float gx = (rx * s + 1.0f) * 1.5f;       // c-axis (k index)
    float gy = (ry * s + 1.0f) * 1.5f;       // b-axis (j index)
    float gz = (rz * s + 1.0f) * 1.5f;       // a-axis (i index)
    float af = floorf(gz), bf = floorf(gy), cf = floorf(gx);
    int ia0 = min(max((int)af, 0), 3);
    int ib0 = min(max((int)bf, 0), 3);
    int ic0 = min(max((int)cf, 0), 3);
    ia[0] = ia0; ia[1] = min(ia0 + 1, 3);
    jb[0] = ib0; jb[1] = min(ib0 + 1, 3);
    kc[0] = ic0; kc[1] = min(ic0 + 1, 3);
    float ad = gz - af, bd = gy - bf, cd = gx - cf;
    wa[0] = 1.0f - ad; wa[1] = ad;
    wb[0] = 1.0f - bd; wb[1] = bd;
    wc[0] = 1.0f - cd; wc[1] = cd;
    return true;
}

// ---------------- edge pass: 8 threads per edge, each owns 2 channels ----------------
// lanes 8k..8k+7 share edge e; per corner each lane loads one 4B half2 -> the 8 lanes
// cover a contiguous 32B run. 2.56M threads / 10008 blocks for latency hiding.
__global__ __launch_bounds__(256) void k_edge(const float* __restrict__ pos,
                                              const int* __restrict__ ei,
                                              const __half* __restrict__ P,
                                              float* __restrict__ out,
                                              int* __restrict__ cnt) {
    long long t = (long long)blockIdx.x * 256 + threadIdx.x;
    int e = (int)(t >> 3);
    int h = (int)(t & 7);            // channel pair: outputs [h*2, h*2+2)
    if (e >= EE) return;
    int row = ei[e];
    int col = ei[EE + e];

    float win;
    int ia[2], jb[2], kc[2];
    float wa[2], wb[2], wc[2];
    bool valid = edge_geom(pos, row, col, win, ia, jb, kc, wa, wb, wc);

    if (valid) {
        float2 acc = make_float2(0.f, 0.f);
        const __half* Pq = P + (size_t)col * 16 + h * 2;
        #pragma unroll
        for (int da = 0; da < 2; ++da)
        #pragma unroll
        for (int db = 0; db < 2; ++db)
        #pragma unroll
        for (int dc = 0; dc < 2; ++dc) {
            float w = wa[da] * wb[db] * wc[dc] * win;
            int cell = ia[da]*16 + jb[db]*4 + kc[dc];
            unsigned int raw = *(const unsigned int*)(Pq + (size_t)cell * NN * 16);
            __half2 hv = *(__half2*)&raw;
            float2 p = __half22float2(hv);
            acc.x = fmaf(w, p.x, acc.x);
            acc.y = fmaf(w, p.y, acc.y);
        }
        float* op = out + (size_t)row * 16 + h * 2;
        atomicAdd(op+0, acc.x);
        atomicAdd(op+1, acc.y);
    }
    if (h == 0) atomicAdd(&cnt[row], 1);
}

// ---------------- fallback: direct edge kernel, filters from global (slow but correct) ----------------
__global__ __launch_bounds__(256) void k_edge_direct(const float* __restrict__ pos,
                                                     const float* __restrict__ feat,
                                                     const float* __restrict__ filt,
                                                     const int* __restrict__ ei,
                                                     float* __restrict__ out,
                                                     int* __restrict__ cnt) {
    int e = blockIdx.x * 256 + threadIdx.x;
    if (e >= EE) return;
    int row = ei[e];
    int col = ei[EE + e];
    atomicAdd(&cnt[row], 1);

    float win;
    int ia[2], jb[2], kc[2];
    float wa[2], wb[2], wc[2];
    if (!edge_geom(pos, row, col, win, ia, jb, kc, wa, wb, wc)) return;

    float fv[16];
    const float4* fp = (const float4*)(feat + (size_t)col * 16);
    float4 f0 = fp[0], f1 = fp[1], f2 = fp[2], f3 = fp[3];
    fv[0]=f0.x; fv[1]=f0.y; fv[2]=f0.z; fv[3]=f0.w;
    fv[4]=f1.x; fv[5]=f1.y; fv[6]=f1.z; fv[7]=f1.w;
    fv[8]=f2.x; fv[9]=f2.y; fv[10]=f2.z; fv[11]=f2.w;
    fv[12]=f3.x; fv[13]=f3.y; fv[14]=f3.z; fv[15]=f3.w;

    float4 a0 = make_float4(0.f,0.f,0.f,0.f);
    float4 a1 = a0, a2 = a0, a3 = a0;
    for (int da = 0; da < 2; ++da)
    for (int db = 0; db < 2; ++db)
    for (int dc = 0; dc < 2; ++dc) {
        float w = wa[da] * wb[db] * wc[dc] * win;
        const float* fb = filt + (size_t)(ia[da]*16 + jb[db]*4 + kc[dc]) * 256;
        #pragma unroll
        for (int ci = 0; ci < 16; ++ci) {
            float c = w * fv[ci];
            const float4* r4 = (const float4*)(fb + ci * 16);
            float4 w0 = r4[0], w1 = r4[1], w2 = r4[2], w3 = r4[3];
            a0.x = fmaf(c, w0.x, a0.x); a0.y = fmaf(c, w0.y, a0.y);
            a0.z = fmaf(c, w0.z, a0.z); a0.w = fmaf(c, w0.w, a0.w);
            a1.x = fmaf(c, w1.x, a1.x); a1.y = fmaf(c, w1.y, a1.y);
            a1.z = fmaf(c, w1.z, a1.z); a1.w = fmaf(c, w1.w, a1.w);
            a2.x = fmaf(c, w2.x, a2.x); a2.y = fmaf(c, w2.y, a2.y);
            a2.z = fmaf(c, w2.z, a2.z); a2.w = fmaf(c, w2.w, a2.w);
            a3.x = fmaf(c, w3.x, a3.x); a3.y = fmaf(c, w3.y, a3.y);
            a3.z = fmaf(c, w3.z, a3.z); a3.w = fmaf(c, w3.w, a3.w);
        }
    }
    float* op = out + (size_t)row * 16;
    atomicAdd(op+0,  a0.x); atomicAdd(op+1,  a0.y); atomicAdd(op+2,  a0.z); atomicAdd(op+3,  a0.w);
    atomicAdd(op+4,  a1.x); atomicAdd(op+5,  a1.y); atomicAdd(op+6,  a1.z); atomicAdd(op+7,  a1.w);
    atomicAdd(op+8,  a2.x); atomicAdd(op+9,  a2.y); atomicAdd(op+10, a2.z); atomicAdd(op+11, a2.w);
    atomicAdd(op+12, a3.x); atomicAdd(op+13, a3.y); atomicAdd(op+14, a3.z); atomicAdd(op+15, a3.w);
}

// ---------------- divide by max(cnt,1) ----------------
__global__ __launch_bounds__(256) void k_div(float* __restrict__ out, const int* __restrict__ cnt) {
    int i = blockIdx.x * 256 + threadIdx.x;
    if (i >= NN * COUT) return;
    int c = cnt[i >> 4];
    float denom = (c > 1) ? (float)c : 1.0f;
    out[i] = out[i] / denom;
}

extern "C" void kernel_launch(void* const* d_in, const int* in_sizes, int n_in,
                              void* d_out, int out_size, void* d_ws, size_t ws_size,
                              hipStream_t stream) {
    const float* pos  = (const float*)d_in[0];
    const float* feat = (const float*)d_in[1];
    const float* filt = (const float*)d_in[2];
    const int*   ei   = (const int*)d_in[3];
    float* out = (float*)d_out;

    int* cnt = (int*)d_ws;
    size_t need = (size_t)P_OFF + (size_t)64 * NN * 16 * sizeof(__half);

    k_zero<<<(NN * COUT + 255) / 256, 256, 0, stream>>>(out, cnt);

    if (ws_size >= need) {
        __half* P = (__half*)((char*)d_ws + P_OFF);
        dim3 pg((NN + 63) / 64, 4);
        k_pgemm<<<pg, 256, 0, stream>>>(feat, filt, P);
        long long tot = (long long)EE * 8;
        k_edge<<<(int)((tot + 255) / 256), 256, 0, stream>>>(pos, ei, P, out, cnt);
    } else {
        k_edge_direct<<<(EE + 255) / 256, 256, 0, stream>>>(pos, feat, filt, ei, out, cnt);
    }

    k_div<<<(NN * COUT + 255) / 256, 256, 0, stream>>>(out, cnt);
}

// Round 9
// 106.291 us; speedup vs baseline: 1.3011x; 1.0226x over previous
//
#include <hip/hip_runtime.h>
#include <hip/hip_fp16.h>
#include <math.h>

#define NN 20000
#define EE 320000
#define CIN 16
#define COUT 16
#define R2C 0.25f
#define MAXDEG 64
// workspace layout:
//   cnt_all : int[NN]  @ 0        (all incident edges, for the mean divisor)
//   slotc   : int[NN]  @ 81920    (valid-edge slot counters)
//   P       : half[64*NN*16] @ 163840                  (41.0 MB)
//   conv    : half[NN*MAXDEG*16] @ 163840+40960000     (41.0 MB)
#define SLOTC_OFF 81920
#define P_OFF     163840
#define CONV_OFF  (163840 + 40960000)

// ---------------- fallback-path zero (out + counters) ----------------
__global__ __launch_bounds__(256) void k_zero(float* __restrict__ out, int* __restrict__ cnt) {
    int i = blockIdx.x * 256 + threadIdx.x;
    if (i < NN * COUT) out[i] = 0.0f;
    if (i < NN) cnt[i] = 0;
}

// ---------------- P GEMM: P[cell][n][o] = sum_ci feat[n][ci] * filters[cell][ci][o] ----------------
// Grid (ceil(NN/64), 4). blockIdx.y==0 blocks also zero the two counter arrays
// (safe: k_edge_store launches after this kernel completes).
__global__ __launch_bounds__(256) void k_pgemm(const float* __restrict__ feat,
                                               const float* __restrict__ filt,
                                               __half* __restrict__ P,
                                               int* __restrict__ cnt_all,
                                               int* __restrict__ slotc) {
    __shared__ float fl[16 * 256]; // 16 cells * 16ci * 16co

    if (blockIdx.y == 0) {
        int g = blockIdx.x * 256 + threadIdx.x;
        if (g < NN) { cnt_all[g] = 0; slotc[g] = 0; }
    }

    {
        const float4* src = (const float4*)(filt + (size_t)blockIdx.y * 16 * 256);
        float4* dst = (float4*)fl;
        #pragma unroll
        for (int r = 0; r < 4; ++r)
            dst[r * 256 + threadIdx.x] = src[r * 256 + threadIdx.x];
    }
    __syncthreads();

    int lane  = threadIdx.x & 63;
    int w     = threadIdx.x >> 6;   // wave -> cell sub-group
    int q     = lane & 3;           // output quad
    int ns    = lane >> 2;          // node sub 0..15
    int nbase = blockIdx.x * 64;

    float f[4][16];
    #pragma unroll
    for (int r = 0; r < 4; ++r) {
        int n = nbase + ns + 16 * r;
        if (n < NN) {
            const float4* fp = (const float4*)(feat + (size_t)n * 16);
            float4 f0 = fp[0], f1 = fp[1], f2 = fp[2], f3 = fp[3];
            f[r][0]=f0.x; f[r][1]=f0.y; f[r][2]=f0.z; f[r][3]=f0.w;
            f[r][4]=f1.x; f[r][5]=f1.y; f[r][6]=f1.z; f[r][7]=f1.w;
            f[r][8]=f2.x; f[r][9]=f2.y; f[r][10]=f2.z; f[r][11]=f2.w;
            f[r][12]=f3.x; f[r][13]=f3.y; f[r][14]=f3.z; f[r][15]=f3.w;
        } else {
            #pragma unroll
            for (int ci = 0; ci < 16; ++ci) f[r][ci] = 0.0f;
        }
    }

    #pragma unroll
    for (int c = 0; c < 4; ++c) {
        int cell = w * 4 + c;
        float4 acc0 = make_float4(0.f,0.f,0.f,0.f);
        float4 acc1 = acc0, acc2 = acc0, acc3 = acc0;
        const float4* row = (const float4*)(fl + cell * 256) + q;
        #pragma unroll
        for (int ci = 0; ci < 16; ++ci) {
            float4 wv = row[ci * 4];
            float v0 = f[0][ci], v1 = f[1][ci], v2 = f[2][ci], v3 = f[3][ci];
            acc0.x = fmaf(v0, wv.x, acc0.x); acc0.y = fmaf(v0, wv.y, acc0.y);
            acc0.z = fmaf(v0, wv.z, acc0.z); acc0.w = fmaf(v0, wv.w, acc0.w);
            acc1.x = fmaf(v1, wv.x, acc1.x); acc1.y = fmaf(v1, wv.y, acc1.y);
            acc1.z = fmaf(v1, wv.z, acc1.z); acc1.w = fmaf(v1, wv.w, acc1.w);
            acc2.x = fmaf(v2, wv.x, acc2.x); acc2.y = fmaf(v2, wv.y, acc2.y);
            acc2.z = fmaf(v2, wv.z, acc2.z); acc2.w = fmaf(v2, wv.w, acc2.w);
            acc3.x = fmaf(v3, wv.x, acc3.x); acc3.y = fmaf(v3, wv.y, acc3.y);
            acc3.z = fmaf(v3, wv.z, acc3.z); acc3.w = fmaf(v3, wv.w, acc3.w);
        }
        size_t cell_g = (size_t)(blockIdx.y * 16 + cell);
        float4 accs[4] = {acc0, acc1, acc2, acc3};
        #pragma unroll
        for (int r = 0; r < 4; ++r) {
            int n = nbase + ns + 16 * r;
            if (n < NN) {
                __half2 lo = __float22half2_rn(make_float2(accs[r].x, accs[r].y));
                __half2 hi = __float22half2_rn(make_float2(accs[r].z, accs[r].w));
                uint2 u;
                u.x = *(unsigned int*)&lo;
                u.y = *(unsigned int*)&hi;
                *(uint2*)(P + (cell_g * NN + n) * 16 + q * 4) = u;
            }
        }
    }
}

// ---------------- geometry helper (device inline) ----------------
__device__ __forceinline__ bool edge_geom(const float* __restrict__ pos, int row, int col,
                                          float& win,
                                          int ia[2], int jb[2], int kc[2],
                                          float wa[2], float wb[2], float wc[2]) {
    float rx = pos[col*3+0] - pos[row*3+0];
    float ry = pos[col*3+1] - pos[row*3+1];
    float rz = pos[col*3+2] - pos[row*3+2];
    float d2 = rx*rx + ry*ry + rz*rz;
    if (!(d2 < R2C)) return false;           // window == 0 -> contributes nothing
    float u = 1.0f - d2 / R2C;
    win = u * u * u;
    float nr = sqrtf(d2);
    float s  = tanhf(nr) / (nr + 1e-8f);
    float gx = (rx * s + 1.0f) * 1.5f;       // c-axis (k index)
    float gy = (ry * s + 1.0f) * 1.5f;       // b-axis (j index)
    float gz = (rz * s + 1.0f) * 1.5f;       // a-axis (i index)
    float af = floorf(gz), bf = floorf(gy), cf = floorf(gx);
    int ia0 = min(max((int)af, 0), 3);
    int ib0 = min(max((int)bf, 0), 3);
    int ic0 = min(max((int)cf, 0), 3);
    ia[0] = ia0; ia[1] = min(ia0 + 1, 3);
    jb[0] = ib0; jb[1] = min(ib0 + 1, 3);
    kc[0] = ic0; kc[1] = min(ic0 + 1, 3);
    float ad = gz - af, bd = gy - bf, cd = gx - cf;
    wa[0] = 1.0f - ad; wa[1] = ad;
    wb[0] = 1.0f - bd; wb[1] = bd;
    wc[0] = 1.0f - cd; wc[1] = cd;
    return true;
}

// ---------------- phase 1: per-edge conv, slot-bucketed store (no fp32 atomics) ----------------
// 8 threads per edge (groups of 8 lanes share e; 'valid' and 'e' are group-uniform).
// lane h==0 takes a slot via int atomic; broadcast by shuffle; the 8 lanes store
// the edge's 16 fp16 values as one contiguous 32B group into conv[row][slot][16].
__global__ __launch_bounds__(256) void k_edge_store(const float* __restrict__ pos,
                                                    const int* __restrict__ ei,
                                                    const __half* __restrict__ P,
                                                    __half* __restrict__ conv,
                                                    int* __restrict__ cnt_all,
                                                    int* __restrict__ slotc) {
    long long t = (long long)blockIdx.x * 256 + threadIdx.x;
    int e = (int)(t >> 3);
    int h = (int)(t & 7);            // channel pair: outputs [h*2, h*2+2)
    if (e >= EE) return;
    int row = ei[e];
    int col = ei[EE + e];
    int lane = threadIdx.x & 63;

    if (h == 0) atomicAdd(&cnt_all[row], 1);

    float win;
    int ia[2], jb[2], kc[2];
    float wa[2], wb[2], wc[2];
    bool valid = edge_geom(pos, row, col, win, ia, jb, kc, wa, wb, wc);

    if (valid) {
        int sv = 0;
        if (h == 0) sv = atomicAdd(&slotc[row], 1);
        int slot = __shfl(sv, lane & 56, 64);   // broadcast from group's lane 0

        float2 acc = make_float2(0.f, 0.f);
        const __half* Pq = P + (size_t)col * 16 + h * 2;
        #pragma unroll
        for (int da = 0; da < 2; ++da)
        #pragma unroll
        for (int db = 0; db < 2; ++db)
        #pragma unroll
        for (int dc = 0; dc < 2; ++dc) {
            float w = wa[da] * wb[db] * wc[dc] * win;
            int cell = ia[da]*16 + jb[db]*4 + kc[dc];
            unsigned int raw = *(const unsigned int*)(Pq + (size_t)cell * NN * 16);
            __half2 hv = *(__half2*)&raw;
            float2 p = __half22float2(hv);
            acc.x = fmaf(w, p.x, acc.x);
            acc.y = fmaf(w, p.y, acc.y);
        }
        if (slot < MAXDEG) {
            __half2 hv = __float22half2_rn(acc);
            *(__half2*)(conv + ((size_t)row * MAXDEG + slot) * 16 + h * 2) = hv;
        }
    }
}

// ---------------- phase 2: per-node slot-sum + mean + plain store ----------------
// 8 threads per node; node's slots are contiguous (32B stride) -> sequential reads.
__global__ __launch_bounds__(256) void k_gather(const __half* __restrict__ conv,
                                                const int* __restrict__ cnt_all,
                                                const int* __restrict__ slotc,
                                                float* __restrict__ out) {
    int t = blockIdx.x * 256 + threadIdx.x;
    int n = t >> 3;
    int h = t & 7;
    if (n >= NN) return;
    int deg = min(slotc[n], MAXDEG);
    int ca  = cnt_all[n];
    float2 acc = make_float2(0.f, 0.f);
    const __half* base = conv + (size_t)n * MAXDEG * 16 + h * 2;
    for (int s = 0; s < deg; ++s) {
        __half2 hv = *(const __half2*)(base + (size_t)s * 16);
        float2 p = __half22float2(hv);
        acc.x += p.x;
        acc.y += p.y;
    }
    float inv = 1.0f / (float)max(ca, 1);
    float2 r = make_float2(acc.x * inv, acc.y * inv);
    *(float2*)(out + (size_t)n * 16 + h * 2) = r;
}

// ---------------- fallback: direct edge kernel, filters from global (slow but correct) ----------------
__global__ __launch_bounds__(256) void k_edge_direct(const float* __restrict__ pos,
                                                     const float* __restrict__ feat,
                                                     const float* __restrict__ filt,
                                                     const int* __restrict__ ei,
                                                     float* __restrict__ out,
                                                     int* __restrict__ cnt) {
    int e = blockIdx.x * 256 + threadIdx.x;
    if (e >= EE) return;
    int row = ei[e];
    int col = ei[EE + e];
    atomicAdd(&cnt[row], 1);

    float win;
    int ia[2], jb[2], kc[2];
    float wa[2], wb[2], wc[2];
    if (!edge_geom(pos, row, col, win, ia, jb, kc, wa, wb, wc)) return;

    float fv[16];
    const float4* fp = (const float4*)(feat + (size_t)col * 16);
    float4 f0 = fp[0], f1 = fp[1], f2 = fp[2], f3 = fp[3];
    fv[0]=f0.x; fv[1]=f0.y; fv[2]=f0.z; fv[3]=f0.w;
    fv[4]=f1.x; fv[5]=f1.y; fv[6]=f1.z; fv[7]=f1.w;
    fv[8]=f2.x; fv[9]=f2.y; fv[10]=f2.z; fv[11]=f2.w;
    fv[12]=f3.x; fv[13]=f3.y; fv[14]=f3.z; fv[15]=f3.w;

    float4 a0 = make_float4(0.f,0.f,0.f,0.f);
    float4 a1 = a0, a2 = a0, a3 = a0;
    for (int da = 0; da < 2; ++da)
    for (int db = 0; db < 2; ++db)
    for (int dc = 0; dc < 2; ++dc) {
        float w = wa[da] * wb[db] * wc[dc] * win;
        const float* fb = filt + (size_t)(ia[da]*16 + jb[db]*4 + kc[dc]) * 256;
        #pragma unroll
        for (int ci = 0; ci < 16; ++ci) {
            float c = w * fv[ci];
            const float4* r4 = (const float4*)(fb + ci * 16);
            float4 w0 = r4[0], w1 = r4[1], w2 = r4[2], w3 = r4[3];
            a0.x = fmaf(c, w0.x, a0.x); a0.y = fmaf(c, w0.y, a0.y);
            a0.z = fmaf(c, w0.z, a0.z); a0.w = fmaf(c, w0.w, a0.w);
            a1.x = fmaf(c, w1.x, a1.x); a1.y = fmaf(c, w1.y, a1.y);
            a1.z = fmaf(c, w1.z, a1.z); a1.w = fmaf(c, w1.w, a1.w);
            a2.x = fmaf(c, w2.x, a2.x); a2.y = fmaf(c, w2.y, a2.y);
            a2.z = fmaf(c, w2.z, a2.z); a2.w = fmaf(c, w2.w, a2.w);
            a3.x = fmaf(c, w3.x, a3.x); a3.y = fmaf(c, w3.y, a3.y);
            a3.z = fmaf(c, w3.z, a3.z); a3.w = fmaf(c, w3.w, a3.w);
        }
    }
    float* op = out + (size_t)row * 16;
    atomicAdd(op+0,  a0.x); atomicAdd(op+1,  a0.y); atomicAdd(op+2,  a0.z); atomicAdd(op+3,  a0.w);
    atomicAdd(op+4,  a1.x); atomicAdd(op+5,  a1.y); atomicAdd(op+6,  a1.z); atomicAdd(op+7,  a1.w);
    atomicAdd(op+8,  a2.x); atomicAdd(op+9,  a2.y); atomicAdd(op+10, a2.z); atomicAdd(op+11, a2.w);
    atomicAdd(op+12, a3.x); atomicAdd(op+13, a3.y); atomicAdd(op+14, a3.z); atomicAdd(op+15, a3.w);
}

// ---------------- fallback divide ----------------
__global__ __launch_bounds__(256) void k_div(float* __restrict__ out, const int* __restrict__ cnt) {
    int i = blockIdx.x * 256 + threadIdx.x;
    if (i >= NN * COUT) return;
    int c = cnt[i >> 4];
    float denom = (c > 1) ? (float)c : 1.0f;
    out[i] = out[i] / denom;
}

extern "C" void kernel_launch(void* const* d_in, const int* in_sizes, int n_in,
                              void* d_out, int out_size, void* d_ws, size_t ws_size,
                              hipStream_t stream) {
    const float* pos  = (const float*)d_in[0];
    const float* feat = (const float*)d_in[1];
    const float* filt = (const float*)d_in[2];
    const int*   ei   = (const int*)d_in[3];
    float* out = (float*)d_out;

    int*    cnt_all = (int*)d_ws;
    int*    slotc   = (int*)((char*)d_ws + SLOTC_OFF);
    __half* P       = (__half*)((char*)d_ws + P_OFF);
    __half* conv    = (__half*)((char*)d_ws + CONV_OFF);

    size_t need = (size_t)CONV_OFF + (size_t)NN * MAXDEG * 16 * sizeof(__half);

    if (ws_size >= need) {
        dim3 pg((NN + 63) / 64, 4);
        k_pgemm<<<pg, 256, 0, stream>>>(feat, filt, P, cnt_all, slotc);
        long long tot = (long long)EE * 8;
        k_edge_store<<<(int)((tot + 255) / 256), 256, 0, stream>>>(pos, ei, P, conv, cnt_all, slotc);
        k_gather<<<(NN * 8 + 255) / 256, 256, 0, stream>>>(conv, cnt_all, slotc, out);
    } else {
        k_zero<<<(NN * COUT + 255) / 256, 256, 0, stream>>>(out, cnt_all);
        k_edge_direct<<<(EE + 255) / 256, 256, 0, stream>>>(pos, feat, filt, ei, out, cnt_all);
        k_div<<<(NN * COUT + 255) / 256, 256, 0, stream>>>(out, cnt_all);
    }
}